// Round 1
// baseline (776.375 us; speedup 1.0000x reference)
//
#include <hip/hip_runtime.h>
#include <math.h>

// Problem dims (fixed by reference)
#define T_DIM 512
#define H_DIM 2048
#define I_DIM 1024
#define E_DIM 16
#define NP    2048          // T*K pairs
#define BM    64            // rows (pairs) per chunk
#define MAXCH 48            // worst-case chunks: NP/BM + E_DIM
#define LIST_OFF 256        // int offset of sorted pair list in ws
#define HWS_OFF  4096       // float offset of h buffer in ws (16 KB for meta)
#define KT    64            // K-tile staged per LDS iteration
#define LDP   68            // padded LDS leading dim (64+4, breaks bank stride)

// ---- routing: count pairs per expert ----
__global__ void count_kernel(const int* __restrict__ sel, int* __restrict__ meta) {
    int p = blockIdx.x * 256 + threadIdx.x;
    if (p < NP) atomicAdd(&meta[sel[p]], 1);
}

// ---- routing: BM-aligned segment offsets + chunk->expert map ----
__global__ void plan_kernel(int* __restrict__ meta) {
    if (threadIdx.x != 0 || blockIdx.x != 0) return;
    int off = 0, ci = 0;
    for (int e = 0; e < E_DIM; ++e) {
        int c = meta[e];
        meta[16 + e] = off;                       // write_ptr start (segment base)
        int nch = (c + BM - 1) / BM;
        for (int j = 0; j < nch; ++j) meta[32 + ci++] = e;
        off += nch * BM;
    }
    for (; ci < MAXCH; ++ci) meta[32 + ci] = -1;
}

// ---- routing: scatter pair ids into expert-sorted list ----
__global__ void scatter_kernel(const int* __restrict__ sel, int* __restrict__ meta) {
    int p = blockIdx.x * 256 + threadIdx.x;
    if (p < NP) {
        int e = sel[p];
        int pos = atomicAdd(&meta[16 + e], 1);
        meta[LIST_OFF + pos] = p;
    }
}

// ---- GEMM 1: h = silu(x.w0d^T) * (x.w1d^T) for each pair, 64x64 tile ----
__global__ __launch_bounds__(256) void gemm01_kernel(
    const float* __restrict__ x, const float* __restrict__ w0g,
    const float* __restrict__ w1g, const float* __restrict__ s0,
    const float* __restrict__ s1, const int* __restrict__ meta,
    float* __restrict__ hbuf) {
    int e = meta[32 + blockIdx.x];
    if (e < 0) return;
    int itile = blockIdx.y;                 // 0..15 (I/64)
    int tid = threadIdx.x;
    int tx = tid & 15, ty = tid >> 4;

    __shared__ float xs[KT][LDP];
    __shared__ float as[KT][LDP];
    __shared__ float bs[KT][LDP];
    __shared__ int prow[BM];
    __shared__ int trow[BM];

    if (tid < BM) {
        int p = meta[LIST_OFF + blockIdx.x * BM + tid];
        prow[tid] = p;
        trow[tid] = p >= 0 ? (p >> 2) : 0;  // token = pair/4
    }
    __syncthreads();

    float ga[4][4], ua[4][4];
#pragma unroll
    for (int a = 0; a < 4; ++a)
#pragma unroll
        for (int b = 0; b < 4; ++b) { ga[a][b] = 0.f; ua[a][b] = 0.f; }

    const int ib = itile >> 1;              // i-block (128-wide) for scales
    const int r = tid >> 2;                 // staging row/col 0..63
    const int jb = (tid & 3) * 4;           // staging float4 group
    const float* xrow  = x   + (size_t)trow[r] * H_DIM;
    const float* w0row = w0g + ((size_t)e * I_DIM + itile * 64 + r) * H_DIM;
    const float* w1row = w1g + ((size_t)e * I_DIM + itile * 64 + r) * H_DIM;

    for (int hb = 0; hb < H_DIM / 128; ++hb) {   // 16 scale blocks
        float pg[4][4], pu[4][4];
#pragma unroll
        for (int a = 0; a < 4; ++a)
#pragma unroll
            for (int b = 0; b < 4; ++b) { pg[a][b] = 0.f; pu[a][b] = 0.f; }

#pragma unroll
        for (int sub = 0; sub < 2; ++sub) {
            int h0 = hb * 128 + sub * KT;
            __syncthreads();
#pragma unroll
            for (int q = 0; q < 4; ++q) {
                int j = jb + q;
                float4 v = *(const float4*)(xrow + h0 + j * 4);
                xs[j*4+0][r] = v.x; xs[j*4+1][r] = v.y; xs[j*4+2][r] = v.z; xs[j*4+3][r] = v.w;
                v = *(const float4*)(w0row + h0 + j * 4);
                as[j*4+0][r] = v.x; as[j*4+1][r] = v.y; as[j*4+2][r] = v.z; as[j*4+3][r] = v.w;
                v = *(const float4*)(w1row + h0 + j * 4);
                bs[j*4+0][r] = v.x; bs[j*4+1][r] = v.y; bs[j*4+2][r] = v.z; bs[j*4+3][r] = v.w;
            }
            __syncthreads();
#pragma unroll 8
            for (int kk = 0; kk < KT; ++kk) {
                float4 xv = *(const float4*)&xs[kk][ty * 4];
                float4 av = *(const float4*)&as[kk][tx * 4];
                float4 bv = *(const float4*)&bs[kk][tx * 4];
                float xr[4] = {xv.x, xv.y, xv.z, xv.w};
                float ar[4] = {av.x, av.y, av.z, av.w};
                float br[4] = {bv.x, bv.y, bv.z, bv.w};
#pragma unroll
                for (int a = 0; a < 4; ++a)
#pragma unroll
                    for (int b = 0; b < 4; ++b) {
                        pg[a][b] = fmaf(xr[a], ar[b], pg[a][b]);
                        pu[a][b] = fmaf(xr[a], br[b], pu[a][b]);
                    }
            }
        }
        float sg = s0[((size_t)e * (I_DIM/128) + ib) * (H_DIM/128) + hb];
        float su = s1[((size_t)e * (I_DIM/128) + ib) * (H_DIM/128) + hb];
#pragma unroll
        for (int a = 0; a < 4; ++a)
#pragma unroll
            for (int b = 0; b < 4; ++b) {
                ga[a][b] = fmaf(pg[a][b], sg, ga[a][b]);
                ua[a][b] = fmaf(pu[a][b], su, ua[a][b]);
            }
    }

    int colbase = itile * 64 + tx * 4;
#pragma unroll
    for (int a = 0; a < 4; ++a) {
        int p = prow[ty * 4 + a];
        if (p < 0) continue;
        float4 hv;
        {
            float g = ga[a][0], u = ua[a][0];
            hv.x = g / (1.f + __expf(-g)) * u;
            g = ga[a][1]; u = ua[a][1];
            hv.y = g / (1.f + __expf(-g)) * u;
            g = ga[a][2]; u = ua[a][2];
            hv.z = g / (1.f + __expf(-g)) * u;
            g = ga[a][3]; u = ua[a][3];
            hv.w = g / (1.f + __expf(-g)) * u;
        }
        *(float4*)(hbuf + (size_t)p * I_DIM + colbase) = hv;
    }
}

// ---- GEMM 2: out[p,:] = (h.w2d^T) * rw[p] ----
__global__ __launch_bounds__(256) void gemm2_kernel(
    const float* __restrict__ hbuf, const float* __restrict__ w2g,
    const float* __restrict__ s2, const float* __restrict__ rw,
    const int* __restrict__ meta, float* __restrict__ out) {
    int e = meta[32 + blockIdx.x];
    if (e < 0) return;
    int htile = blockIdx.y;                 // 0..31 (H/64)
    int tid = threadIdx.x;
    int tx = tid & 15, ty = tid >> 4;

    __shared__ float hs[KT][LDP];
    __shared__ float w2s[KT][LDP];
    __shared__ int prow[BM];

    if (tid < BM) prow[tid] = meta[LIST_OFF + blockIdx.x * BM + tid];
    __syncthreads();

    float ya[4][4];
#pragma unroll
    for (int a = 0; a < 4; ++a)
#pragma unroll
        for (int b = 0; b < 4; ++b) ya[a][b] = 0.f;

    const int hbo = htile >> 1;             // output h-block (128) for scales
    const int r = tid >> 2;
    const int jb = (tid & 3) * 4;
    int pr = prow[r]; if (pr < 0) pr = 0;
    const float* hrow = hbuf + (size_t)pr * I_DIM;
    const float* wrow = w2g + ((size_t)e * H_DIM + htile * 64 + r) * I_DIM;

    for (int iblk = 0; iblk < I_DIM / 128; ++iblk) {   // 8 scale blocks
        float py[4][4];
#pragma unroll
        for (int a = 0; a < 4; ++a)
#pragma unroll
            for (int b = 0; b < 4; ++b) py[a][b] = 0.f;

#pragma unroll
        for (int sub = 0; sub < 2; ++sub) {
            int i0 = iblk * 128 + sub * KT;
            __syncthreads();
#pragma unroll
            for (int q = 0; q < 4; ++q) {
                int j = jb + q;
                float4 v = *(const float4*)(hrow + i0 + j * 4);
                hs[j*4+0][r] = v.x; hs[j*4+1][r] = v.y; hs[j*4+2][r] = v.z; hs[j*4+3][r] = v.w;
                v = *(const float4*)(wrow + i0 + j * 4);
                w2s[j*4+0][r] = v.x; w2s[j*4+1][r] = v.y; w2s[j*4+2][r] = v.z; w2s[j*4+3][r] = v.w;
            }
            __syncthreads();
#pragma unroll 8
            for (int kk = 0; kk < KT; ++kk) {
                float4 hv = *(const float4*)&hs[kk][ty * 4];
                float4 wv = *(const float4*)&w2s[kk][tx * 4];
                float hr[4] = {hv.x, hv.y, hv.z, hv.w};
                float wr[4] = {wv.x, wv.y, wv.z, wv.w};
#pragma unroll
                for (int a = 0; a < 4; ++a)
#pragma unroll
                    for (int b = 0; b < 4; ++b)
                        py[a][b] = fmaf(hr[a], wr[b], py[a][b]);
            }
        }
        float sc = s2[((size_t)e * (H_DIM/128) + hbo) * (I_DIM/128) + iblk];
#pragma unroll
        for (int a = 0; a < 4; ++a)
#pragma unroll
            for (int b = 0; b < 4; ++b)
                ya[a][b] = fmaf(py[a][b], sc, ya[a][b]);
    }

    int colbase = htile * 64 + tx * 4;
#pragma unroll
    for (int a = 0; a < 4; ++a) {
        int p = prow[ty * 4 + a];
        if (p < 0) continue;
        float w = rw[p];
        float4 ov;
        ov.x = ya[a][0] * w; ov.y = ya[a][1] * w;
        ov.z = ya[a][2] * w; ov.w = ya[a][3] * w;
        *(float4*)(out + (size_t)p * H_DIM + colbase) = ov;
    }
}

extern "C" void kernel_launch(void* const* d_in, const int* in_sizes, int n_in,
                              void* d_out, int out_size, void* d_ws, size_t ws_size,
                              hipStream_t stream) {
    const float* x  = (const float*)d_in[0];
    const float* w0 = (const float*)d_in[1];
    const float* w1 = (const float*)d_in[2];
    const float* w2 = (const float*)d_in[3];
    const float* s0 = (const float*)d_in[4];
    const float* s1 = (const float*)d_in[5];
    const float* s2 = (const float*)d_in[6];
    const int* sel  = (const int*)d_in[7];
    const float* rw = (const float*)d_in[8];
    float* out = (float*)d_out;
    int* meta = (int*)d_ws;
    float* hbuf = (float*)d_ws + HWS_OFF;   // 2048*1024 floats = 8 MB

    hipMemsetAsync(meta, 0, 16 * sizeof(int), stream);                    // counts
    hipMemsetAsync(meta + LIST_OFF, 0xFF, MAXCH * BM * sizeof(int), stream); // pair list = -1
    count_kernel<<<NP / 256, 256, 0, stream>>>(sel, meta);
    plan_kernel<<<1, 64, 0, stream>>>(meta);
    scatter_kernel<<<NP / 256, 256, 0, stream>>>(sel, meta);
    gemm01_kernel<<<dim3(MAXCH, I_DIM / 64), 256, 0, stream>>>(x, w0, w1, s0, s1, meta, hbuf);
    gemm2_kernel<<<dim3(MAXCH, H_DIM / 64), 256, 0, stream>>>(hbuf, w2, s2, rw, meta, out);
}

// Round 2
// 463.972 us; speedup vs baseline: 1.6733x; 1.6733x over previous
//
#include <hip/hip_runtime.h>
#include <math.h>

// Problem dims (fixed by reference)
#define T_DIM 512
#define H_DIM 2048
#define I_DIM 1024
#define E_DIM 16
#define NP    2048          // T*K pairs
#define BM    64            // rows (pairs) per chunk
#define MAXCH 48            // worst-case chunks: NP/BM + E_DIM
#define LIST_OFF 256        // int offset of sorted pair list in ws
#define HWS_OFF  4096       // float offset of h buffer in ws
#define BK    128           // K staged per iteration == scale block size
#define LDK   136           // padded bf16 leading dim (272 B stride -> 2-way LDS aliasing = free)

typedef float  float4v __attribute__((ext_vector_type(4)));
typedef short  short8v __attribute__((ext_vector_type(8)));

// f32 -> bf16 round-to-nearest-even (bit pattern)
__device__ __forceinline__ unsigned int bfr(float f) {
    unsigned int u = __builtin_bit_cast(unsigned int, f);
    return (u + 0x7fffu + ((u >> 16) & 1u)) >> 16;
}
__device__ __forceinline__ unsigned int pk2(float a, float b) {
    return bfr(a) | (bfr(b) << 16);
}

// ---- routing: count pairs per expert ----
__global__ void count_kernel(const int* __restrict__ sel, int* __restrict__ meta) {
    int p = blockIdx.x * 256 + threadIdx.x;
    if (p < NP) atomicAdd(&meta[sel[p]], 1);
}

// ---- routing: BM-aligned segment offsets + chunk->expert map ----
__global__ void plan_kernel(int* __restrict__ meta) {
    if (threadIdx.x != 0 || blockIdx.x != 0) return;
    int off = 0, ci = 0;
    for (int e = 0; e < E_DIM; ++e) {
        int c = meta[e];
        meta[16 + e] = off;                       // write_ptr start (segment base)
        int nch = (c + BM - 1) / BM;
        for (int j = 0; j < nch; ++j) meta[32 + ci++] = e;
        off += nch * BM;
    }
    for (; ci < MAXCH; ++ci) meta[32 + ci] = -1;
}

// ---- routing: scatter pair ids into expert-sorted list ----
__global__ void scatter_kernel(const int* __restrict__ sel, int* __restrict__ meta) {
    int p = blockIdx.x * 256 + threadIdx.x;
    if (p < NP) {
        int e = sel[p];
        int pos = atomicAdd(&meta[16 + e], 1);
        meta[LIST_OFF + pos] = p;
    }
}

// ---- GEMM 1 (MFMA bf16): h = silu(x.w0d^T) * (x.w1d^T), 64(pairs) x 64(i) tile ----
// Scale folded into f32->bf16 conversion at staging (scale uniform per tile:
// i-block fixed by itile, h-block fixed by BK=128 chunk).
__global__ __launch_bounds__(256, 3) void gemm01_kernel(
    const float* __restrict__ x, const float* __restrict__ w0g,
    const float* __restrict__ w1g, const float* __restrict__ s0,
    const float* __restrict__ s1, const int* __restrict__ meta,
    unsigned short* __restrict__ hbuf) {
    int e = meta[32 + blockIdx.x];
    if (e < 0) return;
    int itile = blockIdx.y;                 // 0..15 (I/64)
    int tid = threadIdx.x;

    __shared__ unsigned short xs[BM][LDK];
    __shared__ unsigned short as[BM][LDK];
    __shared__ unsigned short bs[BM][LDK];
    __shared__ int prow[BM];
    __shared__ int trow[BM];

    if (tid < BM) {
        int p = meta[LIST_OFF + blockIdx.x * BM + tid];
        prow[tid] = p;
        trow[tid] = p >= 0 ? (p >> 2) : 0;  // token = pair/4
    }
    __syncthreads();

    const int lane = tid & 63;
    const int wid  = tid >> 6;              // wave 0..3 -> m-strip wid*16
    const int l15  = lane & 15;
    const int kq   = (lane >> 4) * 8;       // fragment k sub-offset
    const int ib   = itile >> 1;            // i-block (128) for scales

    float4v zero = {0.f, 0.f, 0.f, 0.f};
    float4v accg[4], accu[4];
#pragma unroll
    for (int t = 0; t < 4; ++t) { accg[t] = zero; accu[t] = zero; }

    const int r  = tid >> 2;                // staging row 0..63
    const int c0 = tid & 3;                 // staging float4 phase
    const float* xrow  = x   + (size_t)trow[r] * H_DIM;
    const float* w0row = w0g + ((size_t)e * I_DIM + itile * 64 + r) * H_DIM;
    const float* w1row = w1g + ((size_t)e * I_DIM + itile * 64 + r) * H_DIM;

    for (int hb = 0; hb < H_DIM / BK; ++hb) {     // 16 chunks == 16 scale blocks
        float sg = s0[((size_t)e * (I_DIM/128) + ib) * (H_DIM/128) + hb];
        float su = s1[((size_t)e * (I_DIM/128) + ib) * (H_DIM/128) + hb];
        const int h0 = hb * BK;
#pragma unroll
        for (int q = 0; q < 8; ++q) {
            int c4 = (c0 + q * 4) * 4;
            float4 v = *(const float4*)(xrow + h0 + c4);
            *(uint2*)&xs[r][c4] = make_uint2(pk2(v.x, v.y), pk2(v.z, v.w));
        }
#pragma unroll
        for (int q = 0; q < 8; ++q) {
            int c4 = (c0 + q * 4) * 4;
            float4 v = *(const float4*)(w0row + h0 + c4);
            *(uint2*)&as[r][c4] = make_uint2(pk2(v.x * sg, v.y * sg), pk2(v.z * sg, v.w * sg));
        }
#pragma unroll
        for (int q = 0; q < 8; ++q) {
            int c4 = (c0 + q * 4) * 4;
            float4 v = *(const float4*)(w1row + h0 + c4);
            *(uint2*)&bs[r][c4] = make_uint2(pk2(v.x * su, v.y * su), pk2(v.z * su, v.w * su));
        }
        __syncthreads();
#pragma unroll
        for (int ks = 0; ks < BK / 32; ++ks) {
            int koff = ks * 32 + kq;
            short8v af = *(const short8v*)&xs[wid * 16 + l15][koff];
#pragma unroll
            for (int nt = 0; nt < 4; ++nt) {
                short8v b0 = *(const short8v*)&as[nt * 16 + l15][koff];
                accg[nt] = __builtin_amdgcn_mfma_f32_16x16x32_bf16(af, b0, accg[nt], 0, 0, 0);
                short8v b1 = *(const short8v*)&bs[nt * 16 + l15][koff];
                accu[nt] = __builtin_amdgcn_mfma_f32_16x16x32_bf16(af, b1, accu[nt], 0, 0, 0);
            }
        }
        __syncthreads();
    }

    // epilogue: C layout col=lane&15 (i), row=(lane>>4)*4+reg (pair)
    int rowb = wid * 16 + (lane >> 4) * 4;
    int colb = itile * 64 + l15;
#pragma unroll
    for (int nt = 0; nt < 4; ++nt) {
#pragma unroll
        for (int rg = 0; rg < 4; ++rg) {
            int p = prow[rowb + rg];
            if (p < 0) continue;
            float g = accg[nt][rg], u = accu[nt][rg];
            float h = g / (1.f + __expf(-g)) * u;
            hbuf[(size_t)p * I_DIM + colb + nt * 16] = (unsigned short)bfr(h);
        }
    }
}

// ---- GEMM 2 (MFMA bf16): out[p,:] = (h.w2d^T) * rw[p], 64(pairs) x 64(h) tile ----
__global__ __launch_bounds__(256, 4) void gemm2_kernel(
    const unsigned short* __restrict__ hbuf, const float* __restrict__ w2g,
    const float* __restrict__ s2, const float* __restrict__ rw,
    const int* __restrict__ meta, float* __restrict__ out) {
    int e = meta[32 + blockIdx.x];
    if (e < 0) return;
    int htile = blockIdx.y;                 // 0..31 (H/64)
    int tid = threadIdx.x;

    __shared__ unsigned short hs[BM][LDK];
    __shared__ unsigned short wsm[BM][LDK];
    __shared__ int prow[BM];

    if (tid < BM) prow[tid] = meta[LIST_OFF + blockIdx.x * BM + tid];
    __syncthreads();

    const int lane = tid & 63;
    const int wid  = tid >> 6;
    const int l15  = lane & 15;
    const int kq   = (lane >> 4) * 8;
    const int hbk  = htile >> 1;            // h-block (128) for scales

    float4v zero = {0.f, 0.f, 0.f, 0.f};
    float4v acc[4];
#pragma unroll
    for (int t = 0; t < 4; ++t) acc[t] = zero;

    const int r  = tid >> 2;
    const int c0 = tid & 3;
    int pr = prow[r]; if (pr < 0) pr = 0;
    const unsigned short* hrow = hbuf + (size_t)pr * I_DIM;
    const float* wrow = w2g + ((size_t)e * H_DIM + htile * 64 + r) * I_DIM;

    for (int ibk = 0; ibk < I_DIM / BK; ++ibk) {  // 8 chunks == 8 scale blocks
        float sc = s2[((size_t)e * (H_DIM/128) + hbk) * (I_DIM/128) + ibk];
        const int i0 = ibk * BK;
#pragma unroll
        for (int q = 0; q < 8; ++q) {
            int c4 = (c0 + q * 4) * 4;
            *(uint2*)&hs[r][c4] = *(const uint2*)(hrow + i0 + c4);   // already bf16
        }
#pragma unroll
        for (int q = 0; q < 8; ++q) {
            int c4 = (c0 + q * 4) * 4;
            float4 v = *(const float4*)(wrow + i0 + c4);
            *(uint2*)&wsm[r][c4] = make_uint2(pk2(v.x * sc, v.y * sc), pk2(v.z * sc, v.w * sc));
        }
        __syncthreads();
#pragma unroll
        for (int ks = 0; ks < BK / 32; ++ks) {
            int koff = ks * 32 + kq;
            short8v af = *(const short8v*)&hs[wid * 16 + l15][koff];
#pragma unroll
            for (int nt = 0; nt < 4; ++nt) {
                short8v bfv = *(const short8v*)&wsm[nt * 16 + l15][koff];
                acc[nt] = __builtin_amdgcn_mfma_f32_16x16x32_bf16(af, bfv, acc[nt], 0, 0, 0);
            }
        }
        __syncthreads();
    }

    int rowb = wid * 16 + (lane >> 4) * 4;
    int colb = htile * 64 + l15;
#pragma unroll
    for (int nt = 0; nt < 4; ++nt) {
#pragma unroll
        for (int rg = 0; rg < 4; ++rg) {
            int p = prow[rowb + rg];
            if (p < 0) continue;
            out[(size_t)p * H_DIM + colb + nt * 16] = acc[nt][rg] * rw[p];
        }
    }
}

extern "C" void kernel_launch(void* const* d_in, const int* in_sizes, int n_in,
                              void* d_out, int out_size, void* d_ws, size_t ws_size,
                              hipStream_t stream) {
    const float* x  = (const float*)d_in[0];
    const float* w0 = (const float*)d_in[1];
    const float* w1 = (const float*)d_in[2];
    const float* w2 = (const float*)d_in[3];
    const float* s0 = (const float*)d_in[4];
    const float* s1 = (const float*)d_in[5];
    const float* s2 = (const float*)d_in[6];
    const int* sel  = (const int*)d_in[7];
    const float* rw = (const float*)d_in[8];
    float* out = (float*)d_out;
    int* meta = (int*)d_ws;
    unsigned short* hbuf = (unsigned short*)((float*)d_ws + HWS_OFF);  // 2048*1024 bf16 = 4 MB

    hipMemsetAsync(meta, 0, 16 * sizeof(int), stream);                       // counts
    hipMemsetAsync(meta + LIST_OFF, 0xFF, MAXCH * BM * sizeof(int), stream); // pair list = -1
    count_kernel<<<NP / 256, 256, 0, stream>>>(sel, meta);
    plan_kernel<<<1, 64, 0, stream>>>(meta);
    scatter_kernel<<<NP / 256, 256, 0, stream>>>(sel, meta);
    gemm01_kernel<<<dim3(MAXCH, I_DIM / 64), 256, 0, stream>>>(x, w0, w1, s0, s1, meta, hbuf);
    gemm2_kernel<<<dim3(MAXCH, H_DIM / 64), 256, 0, stream>>>(hbuf, w2, s2, rw, meta, out);
}

// Round 3
// 452.146 us; speedup vs baseline: 1.7171x; 1.0262x over previous
//
#include <hip/hip_runtime.h>
#include <math.h>

// Problem dims (fixed by reference)
#define T_DIM 512
#define H_DIM 2048
#define I_DIM 1024
#define E_DIM 16
#define NP    2048          // T*K pairs
#define BM    64            // rows (pairs) per chunk
#define MAXCH 48            // worst-case chunks: NP/BM + E_DIM
#define LIST_OFF 256        // int offset of sorted pair list in ws
#define HWS_OFF  4096       // float offset of h buffer in ws
#define BK    128           // K staged per iteration == scale block size
#define LDK   136           // padded bf16 leading dim (272 B stride -> 2-way LDS aliasing = free)

typedef float  float4v __attribute__((ext_vector_type(4)));
typedef short  short8v __attribute__((ext_vector_type(8)));

// f32 -> bf16 round-to-nearest-even (bit pattern)
__device__ __forceinline__ unsigned int bfr(float f) {
    unsigned int u = __builtin_bit_cast(unsigned int, f);
    return (u + 0x7fffu + ((u >> 16) & 1u)) >> 16;
}
__device__ __forceinline__ unsigned int pk2(float a, float b) {
    return bfr(a) | (bfr(b) << 16);
}

// ---- fused routing: count -> plan -> scatter in ONE block ----
__global__ __launch_bounds__(1024) void route_kernel(const int* __restrict__ sel,
                                                     int* __restrict__ meta) {
    __shared__ int cnt[E_DIM];
    __shared__ int wptr[E_DIM];
    int tid = threadIdx.x;
    if (tid < E_DIM) cnt[tid] = 0;
    __syncthreads();
    int p0 = tid, p1 = tid + 1024;
    int e0 = sel[p0], e1 = sel[p1];
    atomicAdd(&cnt[e0], 1);
    atomicAdd(&cnt[e1], 1);
    // init pair list to -1 (padding rows)
    for (int i = tid; i < MAXCH * BM; i += 1024) meta[LIST_OFF + i] = -1;
    __syncthreads();
    if (tid == 0) {
        int off = 0, ci = 0;
        for (int e = 0; e < E_DIM; ++e) {
            wptr[e] = off;
            int nch = (cnt[e] + BM - 1) / BM;
            for (int j = 0; j < nch; ++j) meta[32 + ci++] = e;  // chunk -> expert map
            off += nch * BM;
        }
        for (; ci < MAXCH; ++ci) meta[32 + ci] = -1;
    }
    __syncthreads();
    int pos0 = atomicAdd(&wptr[e0], 1);
    meta[LIST_OFF + pos0] = p0;
    int pos1 = atomicAdd(&wptr[e1], 1);
    meta[LIST_OFF + pos1] = p1;
}

// ---- GEMM 1 (MFMA bf16): h = silu(x.w0d^T) * (x.w1d^T), 64(pairs) x 64(i) tile ----
// Register-prefetch double buffer: chunk hb+1's global loads issue right after
// the staging barrier, hidden behind chunk hb's MFMA phase.
// grid: x = itile (16), y = chunk (48) -> same-expert chunks have linear-id
// delta 16 == 0 mod 8 -> same XCD -> L2 weight reuse.
__global__ __launch_bounds__(256, 2) void gemm01_kernel(
    const float* __restrict__ x, const float* __restrict__ w0g,
    const float* __restrict__ w1g, const float* __restrict__ s0,
    const float* __restrict__ s1, const int* __restrict__ meta,
    unsigned short* __restrict__ hbuf) {
    int e = meta[32 + blockIdx.y];
    if (e < 0) return;
    int itile = blockIdx.x;                 // 0..15 (I/64)
    int tid = threadIdx.x;

    __shared__ unsigned short xs[BM][LDK];
    __shared__ unsigned short as[BM][LDK];
    __shared__ unsigned short bs[BM][LDK];
    __shared__ int prow[BM];
    __shared__ int trow[BM];

    if (tid < BM) {
        int p = meta[LIST_OFF + blockIdx.y * BM + tid];
        prow[tid] = p;
        trow[tid] = p >= 0 ? (p >> 2) : 0;  // token = pair/4
    }
    __syncthreads();

    const int lane = tid & 63;
    const int wid  = tid >> 6;              // wave 0..3 -> m-strip wid*16
    const int l15  = lane & 15;
    const int kq   = (lane >> 4) * 8;       // fragment k sub-offset
    const int ib   = itile >> 1;            // i-block (128) for scales

    float4v zero = {0.f, 0.f, 0.f, 0.f};
    float4v accg[4], accu[4];
#pragma unroll
    for (int t = 0; t < 4; ++t) { accg[t] = zero; accu[t] = zero; }

    const int r  = tid >> 2;                // staging row 0..63
    const int c0 = tid & 3;                 // staging float4 phase
    const float* xrow  = x   + (size_t)trow[r] * H_DIM;
    const float* w0row = w0g + ((size_t)e * I_DIM + itile * 64 + r) * H_DIM;
    const float* w1row = w1g + ((size_t)e * I_DIM + itile * 64 + r) * H_DIM;
    const float* s0p = s0 + ((size_t)e * (I_DIM/128) + ib) * (H_DIM/128);
    const float* s1p = s1 + ((size_t)e * (I_DIM/128) + ib) * (H_DIM/128);

    float4 px[8], pa[8], pb[8];
#pragma unroll
    for (int q = 0; q < 8; ++q) {           // prologue: load chunk 0
        int c4 = (c0 + q * 4) * 4;
        px[q] = *(const float4*)(xrow + c4);
        pa[q] = *(const float4*)(w0row + c4);
        pb[q] = *(const float4*)(w1row + c4);
    }

    for (int hb = 0; hb < H_DIM / BK; ++hb) {     // 16 chunks == 16 scale blocks
        float sg = s0p[hb];
        float su = s1p[hb];
#pragma unroll
        for (int q = 0; q < 8; ++q) {             // regs -> LDS (convert + fold scale)
            int c4 = (c0 + q * 4) * 4;
            *(uint2*)&xs[r][c4] = make_uint2(pk2(px[q].x, px[q].y), pk2(px[q].z, px[q].w));
            *(uint2*)&as[r][c4] = make_uint2(pk2(pa[q].x * sg, pa[q].y * sg),
                                             pk2(pa[q].z * sg, pa[q].w * sg));
            *(uint2*)&bs[r][c4] = make_uint2(pk2(pb[q].x * su, pb[q].y * su),
                                             pk2(pb[q].z * su, pb[q].w * su));
        }
        __syncthreads();
        if (hb + 1 < H_DIM / BK) {                // prefetch next chunk (hidden by MFMA)
            const int h0 = (hb + 1) * BK;
#pragma unroll
            for (int q = 0; q < 8; ++q) {
                int c4 = (c0 + q * 4) * 4;
                px[q] = *(const float4*)(xrow + h0 + c4);
                pa[q] = *(const float4*)(w0row + h0 + c4);
                pb[q] = *(const float4*)(w1row + h0 + c4);
            }
        }
#pragma unroll
        for (int ks = 0; ks < BK / 32; ++ks) {
            int koff = ks * 32 + kq;
            short8v af = *(const short8v*)&xs[wid * 16 + l15][koff];
#pragma unroll
            for (int nt = 0; nt < 4; ++nt) {
                short8v b0 = *(const short8v*)&as[nt * 16 + l15][koff];
                accg[nt] = __builtin_amdgcn_mfma_f32_16x16x32_bf16(af, b0, accg[nt], 0, 0, 0);
                short8v b1 = *(const short8v*)&bs[nt * 16 + l15][koff];
                accu[nt] = __builtin_amdgcn_mfma_f32_16x16x32_bf16(af, b1, accu[nt], 0, 0, 0);
            }
        }
        __syncthreads();
    }

    // epilogue: C layout col=lane&15 (i), row=(lane>>4)*4+reg (pair)
    int rowb = wid * 16 + (lane >> 4) * 4;
    int colb = itile * 64 + l15;
#pragma unroll
    for (int nt = 0; nt < 4; ++nt) {
#pragma unroll
        for (int rg = 0; rg < 4; ++rg) {
            int p = prow[rowb + rg];
            if (p < 0) continue;
            float g = accg[nt][rg], u = accu[nt][rg];
            float h = g / (1.f + __expf(-g)) * u;
            hbuf[(size_t)p * I_DIM + colb + nt * 16] = (unsigned short)bfr(h);
        }
    }
}

// ---- GEMM 2 (MFMA bf16): out[p,:] = (h.w2d^T) * rw[p], 64(pairs) x 64(h) tile ----
// grid: x = htile (32), y = chunk (48) -> same-expert chunks same XCD.
__global__ __launch_bounds__(256, 3) void gemm2_kernel(
    const unsigned short* __restrict__ hbuf, const float* __restrict__ w2g,
    const float* __restrict__ s2, const float* __restrict__ rw,
    const int* __restrict__ meta, float* __restrict__ out) {
    int e = meta[32 + blockIdx.y];
    if (e < 0) return;
    int htile = blockIdx.x;                 // 0..31 (H/64)
    int tid = threadIdx.x;

    __shared__ unsigned short hs[BM][LDK];
    __shared__ unsigned short wsm[BM][LDK];
    __shared__ int prow[BM];

    if (tid < BM) prow[tid] = meta[LIST_OFF + blockIdx.y * BM + tid];
    __syncthreads();

    const int lane = tid & 63;
    const int wid  = tid >> 6;
    const int l15  = lane & 15;
    const int kq   = (lane >> 4) * 8;
    const int hbk  = htile >> 1;            // h-block (128) for scales

    float4v zero = {0.f, 0.f, 0.f, 0.f};
    float4v acc[4];
#pragma unroll
    for (int t = 0; t < 4; ++t) acc[t] = zero;

    const int r  = tid >> 2;
    const int c0 = tid & 3;
    int pr = prow[r]; if (pr < 0) pr = 0;
    const unsigned short* hrow = hbuf + (size_t)pr * I_DIM;
    const float* wrow = w2g + ((size_t)e * H_DIM + htile * 64 + r) * I_DIM;
    const float* s2p = s2 + ((size_t)e * (H_DIM/128) + hbk) * (I_DIM/128);

    uint2  ph[8];
    float4 pw[8];
#pragma unroll
    for (int q = 0; q < 8; ++q) {           // prologue: load chunk 0
        int c4 = (c0 + q * 4) * 4;
        ph[q] = *(const uint2*)(hrow + c4);
        pw[q] = *(const float4*)(wrow + c4);
    }

    for (int ibk = 0; ibk < I_DIM / BK; ++ibk) {  // 8 chunks == 8 scale blocks
        float sc = s2p[ibk];
#pragma unroll
        for (int q = 0; q < 8; ++q) {
            int c4 = (c0 + q * 4) * 4;
            *(uint2*)&hs[r][c4] = ph[q];          // already bf16
            *(uint2*)&wsm[r][c4] = make_uint2(pk2(pw[q].x * sc, pw[q].y * sc),
                                              pk2(pw[q].z * sc, pw[q].w * sc));
        }
        __syncthreads();
        if (ibk + 1 < I_DIM / BK) {               // prefetch next chunk
            const int i0 = (ibk + 1) * BK;
#pragma unroll
            for (int q = 0; q < 8; ++q) {
                int c4 = (c0 + q * 4) * 4;
                ph[q] = *(const uint2*)(hrow + i0 + c4);
                pw[q] = *(const float4*)(wrow + i0 + c4);
            }
        }
#pragma unroll
        for (int ks = 0; ks < BK / 32; ++ks) {
            int koff = ks * 32 + kq;
            short8v af = *(const short8v*)&hs[wid * 16 + l15][koff];
#pragma unroll
            for (int nt = 0; nt < 4; ++nt) {
                short8v bfv = *(const short8v*)&wsm[nt * 16 + l15][koff];
                acc[nt] = __builtin_amdgcn_mfma_f32_16x16x32_bf16(af, bfv, acc[nt], 0, 0, 0);
            }
        }
        __syncthreads();
    }

    int rowb = wid * 16 + (lane >> 4) * 4;
    int colb = htile * 64 + l15;
#pragma unroll
    for (int nt = 0; nt < 4; ++nt) {
#pragma unroll
        for (int rg = 0; rg < 4; ++rg) {
            int p = prow[rowb + rg];
            if (p < 0) continue;
            out[(size_t)p * H_DIM + colb + nt * 16] = acc[nt][rg] * rw[p];
        }
    }
}

extern "C" void kernel_launch(void* const* d_in, const int* in_sizes, int n_in,
                              void* d_out, int out_size, void* d_ws, size_t ws_size,
                              hipStream_t stream) {
    const float* x  = (const float*)d_in[0];
    const float* w0 = (const float*)d_in[1];
    const float* w1 = (const float*)d_in[2];
    const float* w2 = (const float*)d_in[3];
    const float* s0 = (const float*)d_in[4];
    const float* s1 = (const float*)d_in[5];
    const float* s2 = (const float*)d_in[6];
    const int* sel  = (const int*)d_in[7];
    const float* rw = (const float*)d_in[8];
    float* out = (float*)d_out;
    int* meta = (int*)d_ws;
    unsigned short* hbuf = (unsigned short*)((float*)d_ws + HWS_OFF);  // 2048*1024 bf16 = 4 MB

    route_kernel<<<1, 1024, 0, stream>>>(sel, meta);
    gemm01_kernel<<<dim3(I_DIM / 64, MAXCH), 256, 0, stream>>>(x, w0, w1, s0, s1, meta, hbuf);
    gemm2_kernel<<<dim3(H_DIM / 64, MAXCH), 256, 0, stream>>>(hbuf, w2, s2, rw, meta, out);
}